// Round 9
// baseline (257.215 us; speedup 1.0000x reference)
//
#include <hip/hip_runtime.h>
#include <hip/hip_bf16.h>
#include <hip/hip_fp16.h>
#include <cstddef>
#include <cstdint>

// Problem constants
#define BB 2
#define HH 128
#define WW 128
#define CC 256
#define WSZ 8
#define KWIN 16
#define NHEADS 8
#define HD 32
#define C3 768
#define NPIX 32768            // B*H*W
#define NWIN 512              // B * 16 * 16

typedef short    bf16x8 __attribute__((ext_vector_type(8)));
typedef _Float16 half8  __attribute__((ext_vector_type(8)));
typedef float    f32x4  __attribute__((ext_vector_type(4)));

__device__ inline short f2bf(float f) {
    union { float f; unsigned u; } v; v.f = f;
    unsigned r = (v.u + 0x7fffu + ((v.u >> 16) & 1u)) >> 16;
    return (short)r;
}

__device__ inline void gload_lds16(const _Float16* g, _Float16* l) {
    __builtin_amdgcn_global_load_lds(
        (const __attribute__((address_space(1))) unsigned int*)g,
        (__attribute__((address_space(3))) unsigned int*)l, 16, 0, 0);
}

// ---------------------------------------------------------------------------
// CPB MLP: bias_tab[529][8] = sigmoid(relu(tab @ w1 + b1) @ w2) * 16
// ---------------------------------------------------------------------------
__global__ __launch_bounds__(64) void cpb_kernel(const float* __restrict__ w1,
                                                 const float* __restrict__ b1,
                                                 const float* __restrict__ w2,
                                                 float* __restrict__ btab) {
    const int e = blockIdx.x;          // 0..528
    const int i = e / 23, j = e % 23;
    const float inv_log8 = 1.0f / logf(8.0f);
    float c0 = (float)(i - 11) * (8.0f / 7.0f);
    float c1 = (float)(j - 11) * (8.0f / 7.0f);
    float f0 = copysignf(log1pf(fabsf(c0)) * inv_log8, c0);
    float f1 = copysignf(log1pf(fabsf(c1)) * inv_log8, c1);

    const int t = threadIdx.x;
    float acc[8] = {0.f,0.f,0.f,0.f,0.f,0.f,0.f,0.f};
    for (int kk = 0; kk < 8; kk++) {
        int k = kk * 64 + t;
        float hid = f0 * w1[k] + f1 * w1[512 + k] + b1[k];
        hid = fmaxf(hid, 0.f);
        #pragma unroll
        for (int h = 0; h < 8; h++) acc[h] += hid * w2[k * 8 + h];
    }
    #pragma unroll
    for (int h = 0; h < 8; h++) {
        #pragma unroll
        for (int off = 32; off >= 1; off >>= 1) acc[h] += __shfl_xor(acc[h], off);
    }
    if (t < 8) {
        float v = acc[t];
        btab[e * 8 + t] = 16.0f / (1.0f + expf(-v));
    }
}

// ---------------------------------------------------------------------------
// Bake rb into MFMA C-fragment layout, pre-scaled for exp2:
// rbf[h][nt][w][lane][reg] = (btab[row*23+col][h] - M_h) * log2(e)
//   row = w*2 + (quad>>1) + 15 - nt,  col = (quad&1)*4 + reg + 15 - l15
// grid 8*16*4 = 512 blocks, 64 threads.
// ---------------------------------------------------------------------------
__global__ __launch_bounds__(64) void rbfrag_kernel(const float* __restrict__ btab,
                                                    const float* __restrict__ logit_scale,
                                                    float* __restrict__ rbf) {
    const int blk = blockIdx.x;           // ((h*16 + nt)*4 + w)
    const int h = blk >> 6, nt = (blk >> 2) & 15, w = blk & 3;
    const int lane = threadIdx.x, quad = lane >> 4, l15 = lane & 15;
    const float M = __expf(fminf(logit_scale[h], 4.60517019f)) + 16.0f;
    const int row = w * 2 + (quad >> 1) + 15 - nt;
    const int colb = (quad & 1) * 4 + 15 - l15;
    f32x4 v;
    #pragma unroll
    for (int reg = 0; reg < 4; reg++)
        v[reg] = (btab[(row * 23 + colb + reg) * 8 + h] - M) * 1.44269504f;
    *(f32x4*)(rbf + (size_t)blk * 256 + lane * 4) = v;
}

// ---------------------------------------------------------------------------
// depthwise weights fp32 -> fp16 table (9*768 elems)
// ---------------------------------------------------------------------------
__global__ __launch_bounds__(256) void cvt_wdw(const float* __restrict__ src,
                                               _Float16* __restrict__ dst) {
    int i = blockIdx.x * 256 + threadIdx.x;
    if (i < 9 * C3) dst[i] = (_Float16)src[i];
}

// ---------------------------------------------------------------------------
// transpose + convert: src fp32 [R][Cn] -> dst fp16 [Cn][R].  32x32 LDS tile.
// ---------------------------------------------------------------------------
__global__ __launch_bounds__(256) void transpose_cvt(const float* __restrict__ src,
                                                     _Float16* __restrict__ dst,
                                                     int R, int Cn) {
    __shared__ float t[32][33];
    const int bx = blockIdx.x, by = blockIdx.y;
    const int tx = threadIdx.x & 31, ty = threadIdx.x >> 5;
    #pragma unroll
    for (int i = 0; i < 4; i++) {
        int r = by * 32 + ty + i * 8;
        t[ty + i * 8][tx] = src[(size_t)r * Cn + bx * 32 + tx];
    }
    __syncthreads();
    #pragma unroll
    for (int i = 0; i < 4; i++) {
        int dr = bx * 32 + ty + i * 8;          // orig col
        dst[(size_t)dr * R + by * 32 + tx] = (_Float16)t[tx][ty + i * 8];
    }
}

// ---------------------------------------------------------------------------
// fp16 MFMA NT-GEMM:  C[M][N] = A[M][K] * Bt[N][K]^T, fp32 accumulate.
// 128x128 tile, BK=64, 256 threads (4 waves, 2x2 of 64x64).
// LDS layout contract: physical k-slot p at row m holds logical group
// p ^ (m&7); fragment reads undo via phys = logical ^ (l15&7).
// ---------------------------------------------------------------------------
template <typename OT>
__global__ __launch_bounds__(256) void gemm_f16(const _Float16* __restrict__ A,
                                                const _Float16* __restrict__ Bt,
                                                OT* __restrict__ C,
                                                int M, int N, int K) {
    __shared__ _Float16 Ash[128][64];
    __shared__ _Float16 Bsh[128][64];
    const int tid = threadIdx.x;
    const int wv = tid >> 6, ln = tid & 63;
    const int quad = ln >> 4, l15 = ln & 15;
    const int rowb = blockIdx.y * 128;
    const int colb = blockIdx.x * 128;
    const int wm = (wv >> 1) * 64, wn = (wv & 1) * 64;

    const int r8 = ln >> 3, g = ln & 7;
    const int kg = g ^ r8;                    // swizzled logical k-group

    f32x4 acc[4][4] = {};
    for (int k0 = 0; k0 < K; k0 += 64) {
        #pragma unroll
        for (int i = 0; i < 4; i++) {
            const int m = wv * 32 + i * 8 + r8;
            gload_lds16(A + (size_t)(rowb + m) * K + k0 + kg * 8,
                        &Ash[wv * 32 + i * 8][0]);
            gload_lds16(Bt + (size_t)(colb + m) * K + k0 + kg * 8,
                        &Bsh[wv * 32 + i * 8][0]);
        }
        __syncthreads();
        #pragma unroll
        for (int kk = 0; kk < 2; kk++) {
            const int phys = ((kk * 4 + quad) ^ (l15 & 7)) * 8;
            half8 a[4], b[4];
            #pragma unroll
            for (int i = 0; i < 4; i++)
                a[i] = *(const half8*)&Ash[wm + i * 16 + l15][phys];
            #pragma unroll
            for (int j = 0; j < 4; j++)
                b[j] = *(const half8*)&Bsh[wn + j * 16 + l15][phys];
            #pragma unroll
            for (int i = 0; i < 4; i++)
                #pragma unroll
                for (int j = 0; j < 4; j++)
                    acc[i][j] = __builtin_amdgcn_mfma_f32_16x16x32_f16(
                        a[i], b[j], acc[i][j], 0, 0, 0);
        }
        __syncthreads();
    }
    #pragma unroll
    for (int i = 0; i < 4; i++) {
        #pragma unroll
        for (int reg = 0; reg < 4; reg++) {
            const size_t row = rowb + wm + i * 16 + quad * 4 + reg;
            #pragma unroll
            for (int j = 0; j < 4; j++) {
                C[row * N + colb + wn + j * 16 + l15] = (OT)acc[i][j][reg];
            }
        }
    }
}

// ---------------------------------------------------------------------------
// qkv GEMM with fused fp32->fp16 A conversion (A = x fp32 [M][K]).
// Lane loads logical group g, writes phys slot g^r8 (layout contract).
// ---------------------------------------------------------------------------
__global__ __launch_bounds__(256) void gemm_qkv(const float* __restrict__ A,
                                                const _Float16* __restrict__ Bt,
                                                _Float16* __restrict__ C,
                                                int M, int N, int K) {
    __shared__ _Float16 Ash[128][64];
    __shared__ _Float16 Bsh[128][64];
    const int tid = threadIdx.x;
    const int wv = tid >> 6, ln = tid & 63;
    const int quad = ln >> 4, l15 = ln & 15;
    const int rowb = blockIdx.y * 128;
    const int colb = blockIdx.x * 128;
    const int wm = (wv >> 1) * 64, wn = (wv & 1) * 64;
    const int r8 = ln >> 3, g = ln & 7;
    const int kg = g ^ r8;

    f32x4 acc[4][4] = {};
    for (int k0 = 0; k0 < K; k0 += 64) {
        #pragma unroll
        for (int i = 0; i < 4; i++) {
            const int m = wv * 32 + i * 8 + r8;
            const float* ap = A + (size_t)(rowb + m) * K + k0 + g * 8;
            const float4 a0 = *(const float4*)ap;
            const float4 a1 = *(const float4*)(ap + 4);
            half8 hv;
            hv[0] = (_Float16)a0.x; hv[1] = (_Float16)a0.y;
            hv[2] = (_Float16)a0.z; hv[3] = (_Float16)a0.w;
            hv[4] = (_Float16)a1.x; hv[5] = (_Float16)a1.y;
            hv[6] = (_Float16)a1.z; hv[7] = (_Float16)a1.w;
            *(half8*)&Ash[wv * 32 + i * 8 + r8][kg * 8] = hv;
            gload_lds16(Bt + (size_t)(colb + m) * K + k0 + kg * 8,
                        &Bsh[wv * 32 + i * 8][0]);
        }
        __syncthreads();
        #pragma unroll
        for (int kk = 0; kk < 2; kk++) {
            const int phys = ((kk * 4 + quad) ^ (l15 & 7)) * 8;
            half8 a[4], b[4];
            #pragma unroll
            for (int i = 0; i < 4; i++)
                a[i] = *(const half8*)&Ash[wm + i * 16 + l15][phys];
            #pragma unroll
            for (int j = 0; j < 4; j++)
                b[j] = *(const half8*)&Bsh[wn + j * 16 + l15][phys];
            #pragma unroll
            for (int i = 0; i < 4; i++)
                #pragma unroll
                for (int j = 0; j < 4; j++)
                    acc[i][j] = __builtin_amdgcn_mfma_f32_16x16x32_f16(
                        a[i], b[j], acc[i][j], 0, 0, 0);
        }
        __syncthreads();
    }
    #pragma unroll
    for (int i = 0; i < 4; i++) {
        #pragma unroll
        for (int reg = 0; reg < 4; reg++) {
            const size_t row = rowb + wm + i * 16 + quad * 4 + reg;
            #pragma unroll
            for (int j = 0; j < 4; j++) {
                C[row * N + colb + wn + j * 16 + l15] = (_Float16)acc[i][j][reg];
            }
        }
    }
}

// ---------------------------------------------------------------------------
// Depthwise 3x3 conv (SAME) + LayerNorm(768) + qkv bias add.
// 8-pixel strip, 256 threads, column-XOR LDS swizzle (conflict-free).
// Output: q,k thirds fp16; v third stored as BF16 BITS (consumed by attn PV).
// ---------------------------------------------------------------------------
__global__ __launch_bounds__(256) void dwconv_ln(const _Float16* __restrict__ in,
                                                 const _Float16* __restrict__ wdwh,
                                                 const float* __restrict__ g,
                                                 const float* __restrict__ bt,
                                                 const float* __restrict__ qb,
                                                 const float* __restrict__ vb,
                                                 _Float16* __restrict__ out) {
    __shared__ _Float16 S[2880 * 8];      // 45 KB, swizzled half8 units
    __shared__ float sred[4][8][2];

    const int t = threadIdx.x;
    const int pix0 = blockIdx.x * 8;
    const int b = pix0 >> 14, y = (pix0 >> 7) & 127, x0 = pix0 & 127;

    // ---- input halo -> LDS (2880 units: u = (r*10+c)*96 + grp) ----
    for (int u = t; u < 2880; u += 256) {
        const int r = u / 960, rem = u - r * 960;
        const int c = rem / 96, grp = rem - c * 96;
        const int yy = y + r - 1, xx = x0 + c - 1;
        half8 v = (half8)(_Float16)0;
        if ((unsigned)yy < 128u && (unsigned)xx < 128u)
            v = *(const half8*)(in + (((size_t)(b * 128 + yy) * 128 + xx) * C3)
                                + grp * 8);
        const int phys = (u & ~7) | ((u ^ c) & 7);
        *(half8*)&S[phys * 8] = v;
    }
    __syncthreads();

    // ---- conv: thread (p = t&7, gidx = t>>3) does 24 ch of pixel p ----
    const int p = t & 7, gidx = t >> 3;
    float acc[3][8] = {};
    #pragma unroll
    for (int s = 0; s < 3; s++) {
        const int grp = gidx + s * 32;
        half8 w[9];
        #pragma unroll
        for (int tap = 0; tap < 9; tap++)
            w[tap] = *(const half8*)(wdwh + (tap * 96 + grp) * 8);
        #pragma unroll
        for (int r = 0; r < 3; r++) {
            #pragma unroll
            for (int dx = 0; dx < 3; dx++) {
                const int c = p + dx;
                const int u = (r * 10 + c) * 96 + grp;
                const int phys = (u & ~7) | ((u ^ c) & 7);
                const half8 v = *(const half8*)&S[phys * 8];
                const half8 wt = w[r * 3 + dx];
                #pragma unroll
                for (int i = 0; i < 8; i++)
                    acc[s][i] += (float)v[i] * (float)wt[i];
            }
        }
    }

    // ---- LayerNorm reduction over 768 ch of pixel p ----
    float ls = 0.f, lss = 0.f;
    #pragma unroll
    for (int s = 0; s < 3; s++)
        #pragma unroll
        for (int i = 0; i < 8; i++) { ls += acc[s][i]; lss += acc[s][i] * acc[s][i]; }
    ls  += __shfl_xor(ls, 8);  lss += __shfl_xor(lss, 8);
    ls  += __shfl_xor(ls, 16); lss += __shfl_xor(lss, 16);
    ls  += __shfl_xor(ls, 32); lss += __shfl_xor(lss, 32);
    const int wv = t >> 6, lnid = t & 63;
    if (lnid < 8) { sred[wv][lnid][0] = ls; sred[wv][lnid][1] = lss; }
    __syncthreads();
    const float Ssum  = sred[0][p][0] + sred[1][p][0] + sred[2][p][0] + sred[3][p][0];
    const float SSsum = sred[0][p][1] + sred[1][p][1] + sred[2][p][1] + sred[3][p][1];
    const float mu  = Ssum * (1.0f / 768.0f);
    const float var = SSsum * (1.0f / 768.0f) - mu * mu;
    const float rs  = rsqrtf(var + 1e-5f);

    // ---- scale/shift + q/v bias, store (v third as bf16 bits) ----
    const size_t obase = (size_t)(pix0 + p) * C3;
    #pragma unroll
    for (int s = 0; s < 3; s++) {
        const int ch = gidx * 8 + s * 256;
        const float4 g0 = *(const float4*)(g + ch);
        const float4 g1 = *(const float4*)(g + ch + 4);
        const float4 b0 = *(const float4*)(bt + ch);
        const float4 b1 = *(const float4*)(bt + ch + 4);
        float gg[8] = {g0.x, g0.y, g0.z, g0.w, g1.x, g1.y, g1.z, g1.w};
        float bb[8] = {b0.x, b0.y, b0.z, b0.w, b1.x, b1.y, b1.z, b1.w};
        if (s == 0) {
            const float4 e0 = *(const float4*)(qb + ch);
            const float4 e1 = *(const float4*)(qb + ch + 4);
            bb[0] += e0.x; bb[1] += e0.y; bb[2] += e0.z; bb[3] += e0.w;
            bb[4] += e1.x; bb[5] += e1.y; bb[6] += e1.z; bb[7] += e1.w;
        } else if (s == 2) {
            const float4 e0 = *(const float4*)(vb + ch - 512);
            const float4 e1 = *(const float4*)(vb + ch - 512 + 4);
            bb[0] += e0.x; bb[1] += e0.y; bb[2] += e0.z; bb[3] += e0.w;
            bb[4] += e1.x; bb[5] += e1.y; bb[6] += e1.z; bb[7] += e1.w;
        }
        if (s == 2) {
            bf16x8 o;
            #pragma unroll
            for (int i = 0; i < 8; i++)
                o[i] = f2bf((acc[s][i] - mu) * rs * gg[i] + bb[i]);
            *(bf16x8*)((short*)(out + obase + ch)) = o;
        } else {
            half8 o;
            #pragma unroll
            for (int i = 0; i < 8; i++)
                o[i] = (_Float16)((acc[s][i] - mu) * rs * gg[i] + bb[i]);
            *(half8*)(out + obase + ch) = o;
        }
    }
}

// ---------------------------------------------------------------------------
// MFMA halo window attention v4.
// - rb folded into MFMA accumulator via precomputed C-fragment table rbf
//   (coalesced dwordx4 global loads; no btab in LDS, no per-key adds)
// - exp2 path: Q scaled by lscale*log2e, rbf pre-scaled -> pv = exp2f(s)
// - P stored to Pl via 1-op bf16 truncation; Pl rows padded to 136 shorts
//   (16B-aligned rows, dword stride 68 % 32 = 4 -> no bank-aligned rows)
// Exact softmax, static shift M = scale+16 (min exponent 2^-52).
// ---------------------------------------------------------------------------
__global__ __launch_bounds__(256) void attn_mfma(const _Float16* __restrict__ qkv,
                                                 const float* __restrict__ rbf,
                                                 const float* __restrict__ logit_scale,
                                                 _Float16* __restrict__ out) {
    const int blk = blockIdx.x;
    const int h = blk & 7;
    const int wid = blk >> 3;
    const int b = wid >> 8;
    const int wy = (wid >> 4) & 15;
    const int wx = wid & 15;
    const int tid = threadIdx.x;
    const int wave = tid >> 6, lane = tid & 63;
    const int quad = lane >> 4, l15 = lane & 15;

    __shared__ _Float16 Bf[16 * 64 * 8];  // K in B-frag layout, 16 KB
    __shared__ short Vt[32][264];         // V^T bf16 bits, 16.5 KB
    __shared__ short Pl[4][16][136];      // per-wave P chunk, padded, 17.4 KB

    const float lscale = __expf(fminf(logit_scale[h], 4.60517019f)); // ln(100)

    // ---- stage K (normalize -> f16 frag layout) and V (bf16 bits), 1 key/thread
    {
        const int j = tid;                         // key 0..255
        const int kr = j >> 4, kcc = j & 15;
        const int gy = wy * 8 - 4 + kr, gx = wx * 8 - 4 + kcc;
        const bool inb = ((unsigned)gy < 128u) && ((unsigned)gx < 128u);
        const _Float16* p = qkv +
            (((size_t)(b * 128 + (inb ? gy : 0)) * 128 + (inb ? gx : 0)) * C3) +
            256 + h * HD;
        const short* vp = (const short*)(p + 256);
        float kreg[32];
        float s2 = 0.f;
        #pragma unroll
        for (int d8 = 0; d8 < 4; d8++) {
            half8 kk;
            bf16x8 vv;
            if (inb) { kk = *(const half8*)(p + d8 * 8); vv = *(const bf16x8*)(vp + d8 * 8); }
            else     { kk = (half8)(_Float16)0;          vv = (bf16x8)(short)0; }
            #pragma unroll
            for (int u = 0; u < 8; u++) {
                const float kf = (float)kk[u];
                kreg[d8 * 8 + u] = kf;
                s2 += kf * kf;
                Vt[d8 * 8 + u][j] = vv[u];
            }
        }
        const float r = rsqrtf(fmaxf(s2, 1.55e-5f));
        #pragma unroll
        for (int d8 = 0; d8 < 4; d8++) {
            half8 hv;
            #pragma unroll
            for (int u = 0; u < 8; u++)
                hv[u] = (_Float16)(kreg[d8 * 8 + u] * r);
            // B-frag slot: tile = j>>4, lane = d8*16 + (j&15)
            *(half8*)&Bf[(((j >> 4) * 64) + d8 * 16 + (j & 15)) * 8] = hv;
        }
    }
    __syncthreads();

    // ---- per-wave Q A-fragment (f16), scaled by lscale*log2e ----
    const int qrow = wave * 16 + l15;
    const int qr = qrow >> 3, qc = qrow & 7;
    const int qy = wy * 8 + qr, qx = wx * 8 + qc;
    half8 afrag;
    {
        const _Float16* qp = qkv + (((size_t)(b * 128 + qy) * 128 + qx) * C3) + h * HD + quad * 8;
        half8 q8 = *(const half8*)qp;
        float qf[8];
        float s2 = 0.f;
        #pragma unroll
        for (int u = 0; u < 8; u++) { qf[u] = (float)q8[u]; s2 += qf[u] * qf[u]; }
        s2 += __shfl_xor(s2, 16);
        s2 += __shfl_xor(s2, 32);
        const float rq = rsqrtf(fmaxf(s2, 1.55e-5f)) * lscale * 1.44269504f;
        #pragma unroll
        for (int u = 0; u < 8; u++) afrag[u] = (_Float16)(qf[u] * rq);
    }

    // per-thread rb fragment pointer: rbf[((h*16+nt)*4 + wave)*256 + lane*4]
    const float* rbp = rbf + ((size_t)(h * 16) * 4 + wave) * 256 + lane * 4;

    // ---- two 128-key halves: S tiles -> exp2 -> Pl -> PV ----
    float lsum[4] = {0.f, 0.f, 0.f, 0.f};
    f32x4 d0 = {0.f, 0.f, 0.f, 0.f};
    f32x4 d1 = {0.f, 0.f, 0.f, 0.f};
    #pragma unroll
    for (int hf = 0; hf < 2; hf++) {
        #pragma unroll
        for (int ntl = 0; ntl < 8; ntl++) {
            const int nt = hf * 8 + ntl;
            const f32x4 c = *(const f32x4*)(rbp + nt * 1024);
            half8 bfrag = *(const half8*)&Bf[(nt * 64 + lane) * 8];
            f32x4 s = __builtin_amdgcn_mfma_f32_16x16x32_f16(afrag, bfrag, c, 0, 0, 0);
            #pragma unroll
            for (int reg = 0; reg < 4; reg++) {
                const float pv = exp2f(s[reg]);
                lsum[reg] += pv;
                union { float f; unsigned u; } pb; pb.f = pv;
                Pl[wave][quad * 4 + reg][ntl * 16 + l15] = (short)(pb.u >> 16);
            }
        }
        #pragma unroll
        for (int ch = 0; ch < 4; ch++) {
            const int kb = hf * 128 + ch * 32;
            bf16x8 pa = *(const bf16x8*)&Pl[wave][l15][ch * 32 + quad * 8];
            bf16x8 b0 = *(const bf16x8*)&Vt[l15][kb + quad * 8];
            bf16x8 b1 = *(const bf16x8*)&Vt[l15 + 16][kb + quad * 8];
            d0 = __builtin_amdgcn_mfma_f32_16x16x32_bf16(pa, b0, d0, 0, 0, 0);
            d1 = __builtin_amdgcn_mfma_f32_16x16x32_bf16(pa, b1, d1, 0, 0, 0);
        }
    }
    #pragma unroll
    for (int reg = 0; reg < 4; reg++) {
        float v = lsum[reg];
        v += __shfl_xor(v, 1); v += __shfl_xor(v, 2);
        v += __shfl_xor(v, 4); v += __shfl_xor(v, 8);
        lsum[reg] = 1.0f / v;
    }

    // ---- epilogue ----
    #pragma unroll
    for (int reg = 0; reg < 4; reg++) {
        const int gq = wave * 16 + quad * 4 + reg;
        const int oqr = gq >> 3, oqc = gq & 7;
        const int oy = wy * 8 + oqr, ox = wx * 8 + oqc;
        _Float16* op = out + (((size_t)(b * 128 + oy) * 128 + ox) * CC) + h * HD;
        op[l15]      = (_Float16)(d0[reg] * lsum[reg]);
        op[16 + l15] = (_Float16)(d1[reg] * lsum[reg]);
    }
}

// ---------------------------------------------------------------------------
extern "C" void kernel_launch(void* const* d_in, const int* in_sizes, int n_in,
                              void* d_out, int out_size, void* d_ws, size_t ws_size,
                              hipStream_t stream) {
    const float* x           = (const float*)d_in[0];
    const float* w_qkv       = (const float*)d_in[1];
    const float* w_dw        = (const float*)d_in[2];
    const float* ln_g        = (const float*)d_in[3];
    const float* ln_b        = (const float*)d_in[4];
    const float* q_bias      = (const float*)d_in[5];
    const float* v_bias      = (const float*)d_in[6];
    const float* logit_scale = (const float*)d_in[7];
    const float* cpb_w1      = (const float*)d_in[8];
    const float* cpb_b1      = (const float*)d_in[9];
    const float* cpb_w2      = (const float*)d_in[10];
    const float* w_proj      = (const float*)d_in[11];
    float* out = (float*)d_out;

    char* ws = (char*)d_ws;
    _Float16* qkv0h  = (_Float16*)(ws);                          // 50.33 MB
    _Float16* qkvh   = (_Float16*)(ws + 50331648);               // 50.33 MB
    _Float16* attnh  = (_Float16*)(ws + 100663296);              // 16.78 MB
    _Float16* wqkvT  = (_Float16*)(ws + 117440512);              // 0.39 MB
    _Float16* wprojT = (_Float16*)(ws + 117833728);              // 0.13 MB
    _Float16* wdwh   = (_Float16*)(ws + 117964800);              // 13.8 KB
    float*    btab   = (float*)   (ws + 117981184);              // 16.9 KB
    float*    rbf    = (float*)   (ws + 118013952);              // 512 KB

    cpb_kernel<<<529, 64, 0, stream>>>(cpb_w1, cpb_b1, cpb_w2, btab);
    rbfrag_kernel<<<512, 64, 0, stream>>>(btab, logit_scale, rbf);
    cvt_wdw<<<27, 256, 0, stream>>>(w_dw, wdwh);
    transpose_cvt<<<dim3(C3 / 32, CC / 32), 256, 0, stream>>>(w_qkv, wqkvT, CC, C3);
    transpose_cvt<<<dim3(CC / 32, CC / 32), 256, 0, stream>>>(w_proj, wprojT, CC, CC);

    // qkv0 = x @ w_qkv    (fused fp32->fp16 A convert)
    gemm_qkv<<<dim3(C3 / 128, NPIX / 128), 256, 0, stream>>>(
        x, wqkvT, qkv0h, NPIX, C3, CC);
    // depthwise 3x3 + LN + bias  (8-pixel strips; v third -> bf16 bits)
    dwconv_ln<<<NPIX / 8, 256, 0, stream>>>(qkv0h, wdwh, ln_g, ln_b, q_bias,
                                            v_bias, qkvh);
    // halo window attention
    attn_mfma<<<NWIN * NHEADS, 256, 0, stream>>>(qkvh, rbf, logit_scale, attnh);
    // out = attn_out @ w_proj   (fp32 out)
    gemm_f16<float><<<dim3(CC / 128, NPIX / 128), 256, 0, stream>>>(
        attnh, wprojT, out, NPIX, CC, CC);
}